// Round 1
// baseline (239.917 us; speedup 1.0000x reference)
//
#include <hip/hip_runtime.h>
#include <hip/hip_bf16.h>

// Variable_Attention: out = softmax(relu((x@WQ)(x@WK)^T)/sqrt(128), axis=-1)
// B=16, N=2048, T=96, D=128. All fp32 in/out.
// Strategy: split-fp16 MFMA (hi+lo decomposition, 3 MFMA products) for
// fp32-grade accuracy at fp16 matrix-core rate; fused QK^T+softmax with
// register-resident 32x2048 row-block per workgroup.
// Workspace requirement: ~46.3 MB in d_ws.

typedef _Float16 f16;
typedef _Float16 half4 __attribute__((ext_vector_type(4)));
typedef _Float16 half8 __attribute__((ext_vector_type(8)));
typedef float float4v __attribute__((ext_vector_type(4)));

#define B_ 16
#define N_ 2048
#define T_ 96
#define D_ 128

// ---------------------------------------------------------------------------
// k0a: split x (fp32) into hi/lo fp16 pair. x has B*N*T = 3145728 elems.
// ---------------------------------------------------------------------------
__global__ void k_split_x(const float* __restrict__ x, f16* __restrict__ xh,
                          f16* __restrict__ xl, int n4) {
    int idx = blockIdx.x * 256 + threadIdx.x;
    if (idx >= n4) return;
    float4v v = ((const float4v*)x)[idx];
    half4 h, l;
#pragma unroll
    for (int j = 0; j < 4; ++j) {
        f16 hj = (f16)v[j];
        h[j] = hj;
        l[j] = (f16)(v[j] - (float)hj);
    }
    ((half4*)xh)[idx] = h;
    ((half4*)xl)[idx] = l;
}

// ---------------------------------------------------------------------------
// k0b: split WQ/WK (T x D, row-major) into hi/lo fp16, TRANSPOSED to [D][T]
// so MFMA B-fragments read 8 contiguous k-elements per lane.
// blockIdx.x = 0 -> WQ, 1 -> WK.
// ---------------------------------------------------------------------------
__global__ void k_split_w(const float* __restrict__ WQ, const float* __restrict__ WK,
                          f16* __restrict__ wqh, f16* __restrict__ wql,
                          f16* __restrict__ wkh, f16* __restrict__ wkl) {
    const float* W = blockIdx.x ? WK : WQ;
    f16* ht = blockIdx.x ? wkh : wqh;
    f16* lt = blockIdx.x ? wkl : wql;
    for (int i = threadIdx.x; i < T_ * D_; i += blockDim.x) {
        int t = i / D_;
        int d = i % D_;
        float v = W[i];
        f16 h = (f16)v;
        f16 l = (f16)(v - (float)h);
        ht[d * T_ + t] = h;
        lt[d * T_ + t] = l;
    }
}

// ---------------------------------------------------------------------------
// k1: Q = x@WQ, K = x@WK via split-fp16 MFMA (fp32-accurate), then re-split
// the fp32 results into hi/lo fp16 for the big QK^T GEMM.
// Block = 512 threads (8 waves). Block tile = 128 rows of x.
// Waves 0-3 compute Q rows [w*32,+32); waves 4-7 compute K likewise.
// Per wave: 32x128 output, K-dim 96 (3 ksteps of 32).
// mfma_f32_16x16x32_f16: A lane holds A[lane&15][(lane>>4)*8 + i],
//                        B lane holds B[(lane>>4)*8 + i][lane&15],
//                        C: col=lane&15, row=(lane>>4)*4+reg (m89-verified).
// ---------------------------------------------------------------------------
__global__ __launch_bounds__(512, 2) void k_qk(
        const f16* __restrict__ xh, const f16* __restrict__ xl,
        const f16* __restrict__ wqh, const f16* __restrict__ wql,
        const f16* __restrict__ wkh, const f16* __restrict__ wkl,
        f16* __restrict__ Qh, f16* __restrict__ Ql,
        f16* __restrict__ Kh, f16* __restrict__ Kl) {
    const int lane = threadIdx.x & 63;
    const int wave = threadIdx.x >> 6;
    const int lr = lane & 15;
    const int lk = lane >> 4;
    const int isK = wave >> 2;
    const size_t mrow = (size_t)blockIdx.x * 128 + (wave & 3) * 32;

    const f16* wh = isK ? wkh : wqh;
    const f16* wl = isK ? wkl : wql;
    f16* oh = isK ? Kh : Qh;
    f16* ol = isK ? Kl : Ql;

    // A fragments: x rows (hi and lo), K-dim 96 = 3 ksteps
    half8 aH[2][3], aL[2][3];
#pragma unroll
    for (int mt = 0; mt < 2; ++mt)
#pragma unroll
        for (int ks = 0; ks < 3; ++ks) {
            size_t off = (mrow + mt * 16 + lr) * T_ + ks * 32 + lk * 8;
            aH[mt][ks] = *(const half8*)(xh + off);
            aL[mt][ks] = *(const half8*)(xl + off);
        }

    float4v acc[2][8];
#pragma unroll
    for (int mt = 0; mt < 2; ++mt)
#pragma unroll
        for (int nt = 0; nt < 8; ++nt) {
            float4v z = {0.f, 0.f, 0.f, 0.f};
            acc[mt][nt] = z;
        }

#pragma unroll
    for (int nt = 0; nt < 8; ++nt) {
        half8 bH[3], bL[3];
#pragma unroll
        for (int ks = 0; ks < 3; ++ks) {
            size_t off = (size_t)(nt * 16 + lr) * T_ + ks * 32 + lk * 8;
            bH[ks] = *(const half8*)(wh + off);
            bL[ks] = *(const half8*)(wl + off);
        }
#pragma unroll
        for (int ks = 0; ks < 3; ++ks)
#pragma unroll
            for (int mt = 0; mt < 2; ++mt) {
                acc[mt][nt] = __builtin_amdgcn_mfma_f32_16x16x32_f16(aH[mt][ks], bH[ks], acc[mt][nt], 0, 0, 0);
                acc[mt][nt] = __builtin_amdgcn_mfma_f32_16x16x32_f16(aH[mt][ks], bL[ks], acc[mt][nt], 0, 0, 0);
                acc[mt][nt] = __builtin_amdgcn_mfma_f32_16x16x32_f16(aL[mt][ks], bH[ks], acc[mt][nt], 0, 0, 0);
            }
    }

    // Epilogue: split fp32 result into hi/lo fp16, store row-major [row][128]
#pragma unroll
    for (int mt = 0; mt < 2; ++mt)
#pragma unroll
        for (int nt = 0; nt < 8; ++nt)
#pragma unroll
            for (int r = 0; r < 4; ++r) {
                size_t row = mrow + mt * 16 + lk * 4 + r;
                int col = nt * 16 + lr;
                float v = acc[mt][nt][r];
                f16 h = (f16)v;
                f16 l = (f16)(v - (float)h);
                oh[row * D_ + col] = h;
                ol[row * D_ + col] = l;
            }
}

// ---------------------------------------------------------------------------
// k2: fused QK^T + relu + scale + softmax.
// Block = 512 threads (8 waves); block owns 32 full rows of one batch's
// (2048 x 2048) output. Wave w owns the 32 x 256 column slice [w*256,+256).
// Accumulator: 2 mtiles x 16 ntiles x float4 = 128 VGPR per lane.
// QK^T via split-fp16: Qh*Kh + Qh*Kl + Ql*Kh (384 MFMAs/wave).
// Softmax: per-lane partials -> shfl_xor over the 16-lane col group ->
// LDS cross-wave reduce (32 rows) -> exp/sum -> normalize -> write fp32.
// ---------------------------------------------------------------------------
__global__ __launch_bounds__(512, 2) void k_attn(
        const f16* __restrict__ Qh, const f16* __restrict__ Ql,
        const f16* __restrict__ Kh, const f16* __restrict__ Kl,
        float* __restrict__ out) {
    const int lane = threadIdx.x & 63;
    const int wave = threadIdx.x >> 6;
    const int b = blockIdx.x >> 6;
    const int row0 = (blockIdx.x & 63) << 5;   // 32 rows per block
    const int lr = lane & 15;
    const int lk = lane >> 4;
    const size_t base = (size_t)b * (N_ * D_);

    // Q fragments for the whole K-dim (4 ksteps of 32), hi+lo: 64 VGPR
    half8 aH[2][4], aL[2][4];
#pragma unroll
    for (int mt = 0; mt < 2; ++mt)
#pragma unroll
        for (int ks = 0; ks < 4; ++ks) {
            size_t off = base + (size_t)(row0 + mt * 16 + lr) * D_ + ks * 32 + lk * 8;
            aH[mt][ks] = *(const half8*)(Qh + off);
            aL[mt][ks] = *(const half8*)(Ql + off);
        }

    float4v acc[2][16];
#pragma unroll
    for (int mt = 0; mt < 2; ++mt)
#pragma unroll
        for (int nt = 0; nt < 16; ++nt) {
            float4v z = {0.f, 0.f, 0.f, 0.f};
            acc[mt][nt] = z;
        }

    const int ncol0 = wave << 8;   // 256 cols per wave
#pragma unroll
    for (int nt = 0; nt < 16; ++nt) {
        size_t koff = base + (size_t)(ncol0 + nt * 16 + lr) * D_ + lk * 8;
        half8 bH[4], bL[4];
#pragma unroll
        for (int ks = 0; ks < 4; ++ks) {
            bH[ks] = *(const half8*)(Kh + koff + ks * 32);
            bL[ks] = *(const half8*)(Kl + koff + ks * 32);
        }
#pragma unroll
        for (int ks = 0; ks < 4; ++ks)
#pragma unroll
            for (int mt = 0; mt < 2; ++mt) {
                acc[mt][nt] = __builtin_amdgcn_mfma_f32_16x16x32_f16(aH[mt][ks], bH[ks], acc[mt][nt], 0, 0, 0);
                acc[mt][nt] = __builtin_amdgcn_mfma_f32_16x16x32_f16(aH[mt][ks], bL[ks], acc[mt][nt], 0, 0, 0);
                acc[mt][nt] = __builtin_amdgcn_mfma_f32_16x16x32_f16(aL[mt][ks], bH[ks], acc[mt][nt], 0, 0, 0);
            }
    }

    // ---- relu + scale, row max ----
    const float scale = 0.088388347648318447f;  // 1/sqrt(128)
    float rmax[2][4];
#pragma unroll
    for (int mt = 0; mt < 2; ++mt)
#pragma unroll
        for (int r = 0; r < 4; ++r) rmax[mt][r] = 0.0f;   // relu => max >= 0
#pragma unroll
    for (int mt = 0; mt < 2; ++mt)
#pragma unroll
        for (int nt = 0; nt < 16; ++nt)
#pragma unroll
            for (int r = 0; r < 4; ++r) {
                float v = fmaxf(acc[mt][nt][r], 0.0f) * scale;
                acc[mt][nt][r] = v;
                rmax[mt][r] = fmaxf(rmax[mt][r], v);
            }
#pragma unroll
    for (int mt = 0; mt < 2; ++mt)
#pragma unroll
        for (int r = 0; r < 4; ++r) {
            float m = rmax[mt][r];
            m = fmaxf(m, __shfl_xor(m, 1));
            m = fmaxf(m, __shfl_xor(m, 2));
            m = fmaxf(m, __shfl_xor(m, 4));
            m = fmaxf(m, __shfl_xor(m, 8));
            rmax[mt][r] = m;   // wave-local row max (all 16 col-lanes agree)
        }

    __shared__ float red[8][32];
    __shared__ float stat[32];
    if (lr == 0) {
#pragma unroll
        for (int mt = 0; mt < 2; ++mt)
#pragma unroll
            for (int r = 0; r < 4; ++r)
                red[wave][mt * 16 + lk * 4 + r] = rmax[mt][r];
    }
    __syncthreads();
    if (threadIdx.x < 32) {
        float m = red[0][threadIdx.x];
#pragma unroll
        for (int w = 1; w < 8; ++w) m = fmaxf(m, red[w][threadIdx.x]);
        stat[threadIdx.x] = m;
    }
    __syncthreads();

    float rowm[2][4], rsum[2][4];
#pragma unroll
    for (int mt = 0; mt < 2; ++mt)
#pragma unroll
        for (int r = 0; r < 4; ++r) {
            rowm[mt][r] = stat[mt * 16 + lk * 4 + r];
            rsum[mt][r] = 0.0f;
        }

    // ---- exp, row sum ----
#pragma unroll
    for (int mt = 0; mt < 2; ++mt)
#pragma unroll
        for (int nt = 0; nt < 16; ++nt)
#pragma unroll
            for (int r = 0; r < 4; ++r) {
                float e = __expf(acc[mt][nt][r] - rowm[mt][r]);
                acc[mt][nt][r] = e;
                rsum[mt][r] += e;
            }
#pragma unroll
    for (int mt = 0; mt < 2; ++mt)
#pragma unroll
        for (int r = 0; r < 4; ++r) {
            float s = rsum[mt][r];
            s += __shfl_xor(s, 1);
            s += __shfl_xor(s, 2);
            s += __shfl_xor(s, 4);
            s += __shfl_xor(s, 8);
            rsum[mt][r] = s;
        }
    if (lr == 0) {
#pragma unroll
        for (int mt = 0; mt < 2; ++mt)
#pragma unroll
            for (int r = 0; r < 4; ++r)
                red[wave][mt * 16 + lk * 4 + r] = rsum[mt][r];
    }
    __syncthreads();
    if (threadIdx.x < 32) {
        float s = 0.0f;
#pragma unroll
        for (int w = 0; w < 8; ++w) s += red[w][threadIdx.x];
        stat[threadIdx.x] = s;
    }
    __syncthreads();

    float inv[2][4];
#pragma unroll
    for (int mt = 0; mt < 2; ++mt)
#pragma unroll
        for (int r = 0; r < 4; ++r)
            inv[mt][r] = 1.0f / stat[mt * 16 + lk * 4 + r];

    // ---- normalize + store ----
    const size_t obase = (size_t)b * N_ * N_;
#pragma unroll
    for (int mt = 0; mt < 2; ++mt)
#pragma unroll
        for (int nt = 0; nt < 16; ++nt)
#pragma unroll
            for (int r = 0; r < 4; ++r) {
                int grow = row0 + mt * 16 + lk * 4 + r;
                int col = ncol0 + nt * 16 + lr;
                out[obase + (size_t)grow * N_ + col] = acc[mt][nt][r] * inv[mt][r];
            }
}

// ---------------------------------------------------------------------------
extern "C" void kernel_launch(void* const* d_in, const int* in_sizes, int n_in,
                              void* d_out, int out_size, void* d_ws, size_t ws_size,
                              hipStream_t stream) {
    const float* x  = (const float*)d_in[0];
    const float* WQ = (const float*)d_in[1];
    const float* WK = (const float*)d_in[2];
    float* out = (float*)d_out;

    // Workspace carve-up (256B aligned). Total ~46.3 MB.
    char* ws = (char*)d_ws;
    size_t off = 0;
    auto carve = [&](size_t bytes) -> char* {
        char* p = ws + off;
        off += (bytes + 255) & ~(size_t)255;
        return p;
    };
    const size_t xelems = (size_t)B_ * N_ * T_;     // 3145728
    const size_t qelems = (size_t)B_ * N_ * D_;     // 4194304
    f16* xh  = (f16*)carve(xelems * 2);
    f16* xl  = (f16*)carve(xelems * 2);
    f16* wqh = (f16*)carve((size_t)T_ * D_ * 2);
    f16* wql = (f16*)carve((size_t)T_ * D_ * 2);
    f16* wkh = (f16*)carve((size_t)T_ * D_ * 2);
    f16* wkl = (f16*)carve((size_t)T_ * D_ * 2);
    f16* Qh  = (f16*)carve(qelems * 2);
    f16* Ql  = (f16*)carve(qelems * 2);
    f16* Kh  = (f16*)carve(qelems * 2);
    f16* Kl  = (f16*)carve(qelems * 2);
    (void)ws_size; (void)in_sizes; (void)n_in; (void)out_size;

    // k0a: split x
    int n4 = (int)(xelems / 4);
    k_split_x<<<(n4 + 255) / 256, 256, 0, stream>>>(x, xh, xl, n4);
    // k0b: split + transpose W
    k_split_w<<<2, 256, 0, stream>>>(WQ, WK, wqh, wql, wkh, wkl);
    // k1: Q,K projection (split-fp16 MFMA, fp32 accurate), re-split to f16
    k_qk<<<(B_ * N_) / 128, 512, 0, stream>>>(xh, xl, wqh, wql, wkh, wkl,
                                              Qh, Ql, Kh, Kl);
    // k2: fused QK^T + relu + softmax
    k_attn<<<B_ * (N_ / 32), 512, 0, stream>>>(Qh, Ql, Kh, Kl, out);
}

// Round 2
// 180.619 us; speedup vs baseline: 1.3283x; 1.3283x over previous
//
#include <hip/hip_runtime.h>
#include <hip/hip_bf16.h>

// Variable_Attention: out = softmax(relu((x@WQ)(x@WK)^T)/sqrt(128), axis=-1)
// B=16, N=2048, T=96, D=128. fp32 in/out.
//
// Restructure: QK^T = x M x^T with M = WQ WK^T (96x96).
//   k_split_x : x -> xh+xl (fp16 hi/lo split, error 2^-22 rel)
//   k_m       : M^T (transposed, fp32 exact) -> split mth/mtl
//   k_y       : y = x@M via split-fp16 MFMA (3-term), stored fp32
//   k_attn    : S = y@x^T (split-fp16 MFMA, K=96) fused relu/scale/softmax,
//               B-operand LDS-staged per 128-col chunk, double-buffered with
//               counted vmcnt(6) (T3+T4), conflict-free [k8][row][16B] layout.
// Workspace: ~25.3 MB.

typedef _Float16 f16;
typedef _Float16 half4 __attribute__((ext_vector_type(4)));
typedef _Float16 half8 __attribute__((ext_vector_type(8)));
typedef float float4v __attribute__((ext_vector_type(4)));

#define B_ 16
#define N_ 2048
#define T_ 96
#define D_ 128

// ---------------------------------------------------------------------------
// k_split_x: x (fp32) -> hi/lo fp16 pair.
// ---------------------------------------------------------------------------
__global__ void k_split_x(const float* __restrict__ x, f16* __restrict__ xh,
                          f16* __restrict__ xl, int n4) {
    int idx = blockIdx.x * 256 + threadIdx.x;
    if (idx >= n4) return;
    float4v v = ((const float4v*)x)[idx];
    half4 h, l;
#pragma unroll
    for (int j = 0; j < 4; ++j) {
        f16 hj = (f16)v[j];
        h[j] = hj;
        l[j] = (f16)(v[j] - (float)hj);
    }
    ((half4*)xh)[idx] = h;
    ((half4*)xl)[idx] = l;
}

// ---------------------------------------------------------------------------
// k_m: M[t][t2] = sum_d WQ[t,d]*WK[t2,d]  (fp32 exact), stored TRANSPOSED
// (mt*[t2][t]) and split to fp16 hi/lo so k_y's B-fragments are contiguous.
// ---------------------------------------------------------------------------
__global__ void k_m(const float* __restrict__ WQ, const float* __restrict__ WK,
                    f16* __restrict__ mth, f16* __restrict__ mtl) {
    int i = blockIdx.x * 256 + threadIdx.x;
    if (i >= T_ * T_) return;
    int t = i / T_, t2 = i % T_;
    const float4v* q = (const float4v*)(WQ + (size_t)t * D_);
    const float4v* k = (const float4v*)(WK + (size_t)t2 * D_);
    float s = 0.0f;
#pragma unroll
    for (int d = 0; d < D_ / 4; ++d) {
        float4v a = q[d], b = k[d];
        s += a[0] * b[0] + a[1] * b[1] + a[2] * b[2] + a[3] * b[3];
    }
    f16 h = (f16)s;
    mth[t2 * T_ + t] = h;
    mtl[t2 * T_ + t] = (f16)(s - (float)h);
}

// ---------------------------------------------------------------------------
// k_y: y = x @ M  (32768 x 96, K=96), split-fp16 MFMA 3-term, output fp32.
// 256 threads (4 waves), wave owns 32 rows; block = 128 rows.
// ---------------------------------------------------------------------------
__global__ __launch_bounds__(256) void k_y(
        const f16* __restrict__ xh, const f16* __restrict__ xl,
        const f16* __restrict__ mth, const f16* __restrict__ mtl,
        float* __restrict__ y) {
    const int lane = threadIdx.x & 63;
    const int wave = threadIdx.x >> 6;
    const int lr = lane & 15;
    const int lk = lane >> 4;
    const size_t mrow = (size_t)blockIdx.x * 128 + wave * 32;

    half8 aH[2][3], aL[2][3];
#pragma unroll
    for (int mt = 0; mt < 2; ++mt)
#pragma unroll
        for (int ks = 0; ks < 3; ++ks) {
            size_t off = (mrow + mt * 16 + lr) * T_ + ks * 32 + lk * 8;
            aH[mt][ks] = *(const half8*)(xh + off);
            aL[mt][ks] = *(const half8*)(xl + off);
        }

    float4v acc[2][6];
#pragma unroll
    for (int mt = 0; mt < 2; ++mt)
#pragma unroll
        for (int nt = 0; nt < 6; ++nt) {
            float4v z = {0.f, 0.f, 0.f, 0.f};
            acc[mt][nt] = z;
        }

#pragma unroll
    for (int nt = 0; nt < 6; ++nt) {
        half8 bH[3], bL[3];
#pragma unroll
        for (int ks = 0; ks < 3; ++ks) {
            size_t off = (size_t)(nt * 16 + lr) * T_ + ks * 32 + lk * 8;
            bH[ks] = *(const half8*)(mth + off);
            bL[ks] = *(const half8*)(mtl + off);
        }
#pragma unroll
        for (int ks = 0; ks < 3; ++ks)
#pragma unroll
            for (int mt = 0; mt < 2; ++mt) {
                acc[mt][nt] = __builtin_amdgcn_mfma_f32_16x16x32_f16(aH[mt][ks], bH[ks], acc[mt][nt], 0, 0, 0);
                acc[mt][nt] = __builtin_amdgcn_mfma_f32_16x16x32_f16(aH[mt][ks], bL[ks], acc[mt][nt], 0, 0, 0);
                acc[mt][nt] = __builtin_amdgcn_mfma_f32_16x16x32_f16(aL[mt][ks], bH[ks], acc[mt][nt], 0, 0, 0);
            }
    }

#pragma unroll
    for (int mt = 0; mt < 2; ++mt)
#pragma unroll
        for (int nt = 0; nt < 6; ++nt)
#pragma unroll
            for (int r = 0; r < 4; ++r)
                y[(mrow + mt * 16 + lk * 4 + r) * T_ + nt * 16 + lr] = acc[mt][nt][r];
}

// ---------------------------------------------------------------------------
// k_attn: S = y @ x^T fused with relu/scale/softmax.
// Block = 512 threads (8 waves) owns 32 rows x 2048 cols of one batch.
// Column dim processed as 16 chunks of 128; per chunk all 8 waves share an
// LDS-staged x-slice (hi+lo, 48KB), double-buffered, global_load_lds width=16,
// counted vmcnt(6). Wave w computes cols chunk*128 + w*16 + lr.
// LDS layout [k8][row][8xf16]: linear global_load_lds dest AND conflict-free
// ds_read_b128 (lanes 0..7 span all 32 banks).
// ---------------------------------------------------------------------------
__global__ __launch_bounds__(512, 2) void k_attn(
        const f16* __restrict__ xh, const f16* __restrict__ xl,
        const float* __restrict__ y, float* __restrict__ out) {
    __shared__ __align__(16) f16 ldsb[2][2][12][128][8];   // 96 KB
    __shared__ float red[8][32];
    __shared__ float stat[32];

    const int tid  = (int)threadIdx.x;
    const int lane = tid & 63;
    const int wave = tid >> 6;
    const int lr = lane & 15;
    const int lk = lane >> 4;

    // XCD-aware bijective swizzle (1024 blocks % 8 == 0): each XCD gets a
    // contiguous logical range -> per-XCD L2 holds ~2 batches' x+y (~3.2MB).
    const int lb   = ((int)blockIdx.x & 7) * 128 + ((int)blockIdx.x >> 3);
    const int b    = lb >> 6;
    const int row0 = (lb & 63) << 5;
    const size_t xbase = (size_t)b * N_;        // batch's first row in x/y
    const size_t obase = (size_t)b * N_ * N_;

    // ---- A fragments: y rows (fp32), split on the fly to f16 hi/lo ----
    half8 aH[2][3], aL[2][3];
#pragma unroll
    for (int mt = 0; mt < 2; ++mt)
#pragma unroll
        for (int ks = 0; ks < 3; ++ks) {
            const float* p = y + (xbase + row0 + mt * 16 + lr) * T_ + ks * 32 + lk * 8;
            float4v v0 = *(const float4v*)p;
            float4v v1 = *(const float4v*)(p + 4);
            half8 h, l;
#pragma unroll
            for (int j = 0; j < 4; ++j) {
                f16 h0 = (f16)v0[j]; h[j] = h0; l[j] = (f16)(v0[j] - (float)h0);
                f16 h1 = (f16)v1[j]; h[4 + j] = h1; l[4 + j] = (f16)(v1[j] - (float)h1);
            }
            aH[mt][ks] = h;
            aL[mt][ks] = l;
        }

    float4v acc[2][16];
#pragma unroll
    for (int mt = 0; mt < 2; ++mt)
#pragma unroll
        for (int c = 0; c < 16; ++c) {
            float4v z = {0.f, 0.f, 0.f, 0.f};
            acc[mt][c] = z;
        }

    const f16* const srcs[2] = { xh, xl };
    // Stage chunk (128 x-rows, hi+lo) into ldsb[buf]: 6 global_load_lds x16B
    // per thread-wave set. Dest linear: gci = i*512+tid -> [k8=gci>>7][row=gci&127].
    auto stage = [&](int chunk, int buf) {
#pragma unroll
        for (int hl = 0; hl < 2; ++hl)
#pragma unroll
            for (int i = 0; i < 3; ++i) {
                int gci = i * 512 + tid;
                int k8  = gci >> 7;
                int row = gci & 127;
                const f16* g = srcs[hl] + (xbase + chunk * 128 + row) * T_ + k8 * 8;
                f16* lp = &ldsb[buf][hl][0][0][0] + (size_t)(i * 512 + wave * 64) * 8;
                __builtin_amdgcn_global_load_lds(
                    (const __attribute__((address_space(1))) void*)g,
                    (__attribute__((address_space(3))) void*)lp, 16, 0, 0);
            }
    };

    stage(0, 0);
#pragma unroll
    for (int c = 0; c < 16; ++c) {
        const int buf = c & 1;
        if (c < 15) {
            stage(c + 1, buf ^ 1);
            asm volatile("s_waitcnt vmcnt(6)" ::: "memory");   // prev stage done
        } else {
            asm volatile("s_waitcnt vmcnt(0)" ::: "memory");
        }
        __builtin_amdgcn_s_barrier();
        asm volatile("" ::: "memory");

        half8 bH[3], bL[3];
#pragma unroll
        for (int ks = 0; ks < 3; ++ks) {
            bH[ks] = *(const half8*)&ldsb[buf][0][ks * 4 + lk][wave * 16 + lr][0];
            bL[ks] = *(const half8*)&ldsb[buf][1][ks * 4 + lk][wave * 16 + lr][0];
        }
        __builtin_amdgcn_s_setprio(1);
#pragma unroll
        for (int ks = 0; ks < 3; ++ks)
#pragma unroll
            for (int mt = 0; mt < 2; ++mt) {
                acc[mt][c] = __builtin_amdgcn_mfma_f32_16x16x32_f16(aH[mt][ks], bH[ks], acc[mt][c], 0, 0, 0);
                acc[mt][c] = __builtin_amdgcn_mfma_f32_16x16x32_f16(aH[mt][ks], bL[ks], acc[mt][c], 0, 0, 0);
                acc[mt][c] = __builtin_amdgcn_mfma_f32_16x16x32_f16(aL[mt][ks], bH[ks], acc[mt][c], 0, 0, 0);
            }
        __builtin_amdgcn_s_setprio(0);
        asm volatile("s_waitcnt lgkmcnt(0)" ::: "memory");     // reads drained
        __builtin_amdgcn_s_barrier();                          // buf reusable
        asm volatile("" ::: "memory");
    }

    // ---- relu + scale, row max ----
    const float scale = 0.088388347648318447f;  // 1/sqrt(128)
    float rmax[2][4];
#pragma unroll
    for (int mt = 0; mt < 2; ++mt)
#pragma unroll
        for (int r = 0; r < 4; ++r) rmax[mt][r] = 0.0f;
#pragma unroll
    for (int mt = 0; mt < 2; ++mt)
#pragma unroll
        for (int c = 0; c < 16; ++c)
#pragma unroll
            for (int r = 0; r < 4; ++r) {
                float v = fmaxf(acc[mt][c][r], 0.0f) * scale;
                acc[mt][c][r] = v;
                rmax[mt][r] = fmaxf(rmax[mt][r], v);
            }
#pragma unroll
    for (int mt = 0; mt < 2; ++mt)
#pragma unroll
        for (int r = 0; r < 4; ++r) {
            float m = rmax[mt][r];
            m = fmaxf(m, __shfl_xor(m, 1));
            m = fmaxf(m, __shfl_xor(m, 2));
            m = fmaxf(m, __shfl_xor(m, 4));
            m = fmaxf(m, __shfl_xor(m, 8));
            rmax[mt][r] = m;
        }
    if (lr == 0) {
#pragma unroll
        for (int mt = 0; mt < 2; ++mt)
#pragma unroll
            for (int r = 0; r < 4; ++r)
                red[wave][mt * 16 + lk * 4 + r] = rmax[mt][r];
    }
    __syncthreads();
    if (tid < 32) {
        float m = red[0][tid];
#pragma unroll
        for (int w = 1; w < 8; ++w) m = fmaxf(m, red[w][tid]);
        stat[tid] = m;
    }
    __syncthreads();

    float rowm[2][4], rsum[2][4];
#pragma unroll
    for (int mt = 0; mt < 2; ++mt)
#pragma unroll
        for (int r = 0; r < 4; ++r) {
            rowm[mt][r] = stat[mt * 16 + lk * 4 + r];
            rsum[mt][r] = 0.0f;
        }

    // ---- exp, row sum ----
#pragma unroll
    for (int mt = 0; mt < 2; ++mt)
#pragma unroll
        for (int c = 0; c < 16; ++c)
#pragma unroll
            for (int r = 0; r < 4; ++r) {
                float e = __expf(acc[mt][c][r] - rowm[mt][r]);
                acc[mt][c][r] = e;
                rsum[mt][r] += e;
            }
#pragma unroll
    for (int mt = 0; mt < 2; ++mt)
#pragma unroll
        for (int r = 0; r < 4; ++r) {
            float s = rsum[mt][r];
            s += __shfl_xor(s, 1);
            s += __shfl_xor(s, 2);
            s += __shfl_xor(s, 4);
            s += __shfl_xor(s, 8);
            rsum[mt][r] = s;
        }
    if (lr == 0) {
#pragma unroll
        for (int mt = 0; mt < 2; ++mt)
#pragma unroll
            for (int r = 0; r < 4; ++r)
                red[wave][mt * 16 + lk * 4 + r] = rsum[mt][r];
    }
    __syncthreads();
    if (tid < 32) {
        float s = 0.0f;
#pragma unroll
        for (int w = 0; w < 8; ++w) s += red[w][tid];
        stat[tid] = s;
    }
    __syncthreads();

    float inv[2][4];
#pragma unroll
    for (int mt = 0; mt < 2; ++mt)
#pragma unroll
        for (int r = 0; r < 4; ++r)
            inv[mt][r] = 1.0f / stat[mt * 16 + lk * 4 + r];

    // ---- normalize + store ----
#pragma unroll
    for (int mt = 0; mt < 2; ++mt)
#pragma unroll
        for (int c = 0; c < 16; ++c)
#pragma unroll
            for (int r = 0; r < 4; ++r) {
                int grow = row0 + mt * 16 + lk * 4 + r;
                int col = c * 128 + wave * 16 + lr;
                out[obase + (size_t)grow * N_ + col] = acc[mt][c][r] * inv[mt][r];
            }
}

// ---------------------------------------------------------------------------
extern "C" void kernel_launch(void* const* d_in, const int* in_sizes, int n_in,
                              void* d_out, int out_size, void* d_ws, size_t ws_size,
                              hipStream_t stream) {
    const float* x  = (const float*)d_in[0];
    const float* WQ = (const float*)d_in[1];
    const float* WK = (const float*)d_in[2];
    float* out = (float*)d_out;

    char* ws = (char*)d_ws;
    size_t off = 0;
    auto carve = [&](size_t bytes) -> char* {
        char* p = ws + off;
        off += (bytes + 255) & ~(size_t)255;
        return p;
    };
    const size_t xelems = (size_t)B_ * N_ * T_;   // 3145728
    f16*   xh  = (f16*)carve(xelems * 2);
    f16*   xl  = (f16*)carve(xelems * 2);
    f16*   mth = (f16*)carve((size_t)T_ * T_ * 2);
    f16*   mtl = (f16*)carve((size_t)T_ * T_ * 2);
    float* yw  = (float*)carve((size_t)B_ * N_ * T_ * 4);
    (void)ws_size; (void)in_sizes; (void)n_in; (void)out_size;

    int n4 = (int)(xelems / 4);
    k_split_x<<<(n4 + 255) / 256, 256, 0, stream>>>(x, xh, xl, n4);
    k_m<<<(T_ * T_ + 255) / 256, 256, 0, stream>>>(WQ, WK, mth, mtl);
    k_y<<<(B_ * N_) / 128, 256, 0, stream>>>(xh, xl, mth, mtl, yw);
    k_attn<<<B_ * (N_ / 32), 512, 0, stream>>>(xh, xl, yw, out);
}